// Round 1
// 356.688 us; speedup vs baseline: 1.0129x; 1.0129x over previous
//
#include <hip/hip_runtime.h>
#include <math.h>

// GraphSAGE fused inference, MI355X.
// fc1 is linear and agg0 = mean over n0 of h1, so
// agg0 = concat(mean(e_n), mean_all(e_nn)) @ W1 — no per-neighbor GEMM needed.
//
// R1 change: phase-1 gather rewritten for deep memory-level parallelism.
// Old: unroll-4 + single accumulator => issue 4 loads, drain vmcnt to 0, repeat
// (~10 outstanding 256B loads/CU measured => 87 cyc/load, latency-bound).
// New: batches of 8 independent float4 loads into a register window before any
// accumulate (2 accumulators break the add chain), independent e_n/e_v loads
// hoisted above the 250-row loop. launch_bounds(256,6): 24 waves/CU, VGPR<=84.

constexpr int D   = 64;    // embed dim
constexpr int N0  = 10;
constexpr int N1  = 25;
constexpr int NN  = N0 * N1;   // 250
constexpr int H1  = 128;
constexpr int H0  = 128;
constexpr int K0  = D + H1;    // 192 (fc0 input dim)
constexpr int BPB = 2;         // batch rows per block
constexpr int NT  = 256;       // threads per block

__global__ __launch_bounds__(NT, 6) void sage_fused(
    const int*   __restrict__ inputs,   // [B]
    const int*   __restrict__ neigh0,   // [B, 10]
    const int*   __restrict__ neigh1,   // [B, 10, 25]
    const float* __restrict__ embed,    // [NODE_CNT+1, 64]
    const float* __restrict__ W1,       // [128, 128]
    const float* __restrict__ W0,       // [192, 128]
    const float* __restrict__ b0,       // [128]
    float*       __restrict__ out)      // [B, 128]
{
    __shared__ int   s_idx1[BPB * NN];       // 500 ints
    __shared__ int   s_idx0[BPB * N0];       // 20 ints
    __shared__ int   s_in[BPB];
    __shared__ float part_nn[16][D];         // 4 KB
    __shared__ float part_en[16][D];         // 4 KB
    __shared__ float xbar[BPB][2 * D];       // [r][128] : [e_n mean | nn mean]
    __shared__ float x0s[BPB][K0];           // [r][192] : [e_v | agg0]
    __shared__ float p2[2][BPB][H1];         // half-K partial sums

    const int t     = threadIdx.x;
    const int bbase = blockIdx.x * BPB;

    // ---- stage indices into LDS (coalesced) ----
    for (int i = t; i < BPB * NN; i += NT) s_idx1[i] = neigh1[bbase * NN + i];
    if (t < BPB * N0) s_idx0[t] = neigh0[bbase * N0 + t];
    if (t < BPB)      s_in[t]   = inputs[bbase + t];
    __syncthreads();

    // ---- phase 1: gather + accumulate ----
    // thread -> (slot s, 16B column chunk). 16 lanes cover one 256B row.
    const int c4lane = t & 15;         // 0..15
    const int s      = t >> 4;         // slot 0..15
    const int r      = s & (BPB - 1);  // batch row within block
    const int ss     = s >> 1;         // 0..7 : slot index within row
    const int cOff   = c4lane * 4;     // float column offset
    const float* __restrict__ eb   = embed + cOff;
    const int*   __restrict__ sidx = &s_idx1[r * NN];

    // long-latency independent loads issued FIRST; consumed after the nn loop,
    // so their latency drains under ~4 batches of gather work.
    float4 en0 = *(const float4*)(eb + (size_t)s_idx0[r * N0 + ss] * D);
    float4 en1;
    const bool has_en1 = (ss < 2);     // rows 8,9 of e_n
    if (has_en1) en1 = *(const float4*)(eb + (size_t)s_idx0[r * N0 + ss + 8] * D);
    float4 ev;
    const bool has_ev = (ss == 0);     // e_v row for batch row r
    if (has_ev) ev = *(const float4*)(eb + (size_t)s_in[r] * D);

    // slot ss owns nn rows i = ss + 8*m, m = 0..31 (i < 250).
    float4 a0 = make_float4(0.f, 0.f, 0.f, 0.f);
    float4 a1 = make_float4(0.f, 0.f, 0.f, 0.f);

    #pragma unroll 1
    for (int m0 = 0; m0 < 24; m0 += 8) {
        float4 v[8];
        #pragma unroll
        for (int b = 0; b < 8; ++b)
            v[b] = *(const float4*)(eb + (size_t)sidx[ss + ((m0 + b) << 3)] * D);
        #pragma unroll
        for (int b = 0; b < 8; b += 2) {
            a0.x += v[b].x;   a0.y += v[b].y;   a0.z += v[b].z;   a0.w += v[b].w;
            a1.x += v[b+1].x; a1.y += v[b+1].y; a1.z += v[b+1].z; a1.w += v[b+1].w;
        }
    }
    {   // tail: m = 24..30 valid for all ss; m = 31 (i = ss+248) only for ss<2.
        float4 v[7];
        #pragma unroll
        for (int b = 0; b < 7; ++b)
            v[b] = *(const float4*)(eb + (size_t)sidx[ss + ((24 + b) << 3)] * D);
        float4 vt;
        const bool has_t = (ss < 2);
        if (has_t) vt = *(const float4*)(eb + (size_t)sidx[ss + 248] * D);
        #pragma unroll
        for (int b = 0; b < 7; ++b) {
            if (b & 1) { a1.x += v[b].x; a1.y += v[b].y; a1.z += v[b].z; a1.w += v[b].w; }
            else       { a0.x += v[b].x; a0.y += v[b].y; a0.z += v[b].z; a0.w += v[b].w; }
        }
        if (has_t) { a1.x += vt.x; a1.y += vt.y; a1.z += vt.z; a1.w += vt.w; }
    }

    float4 snn;
    snn.x = a0.x + a1.x; snn.y = a0.y + a1.y; snn.z = a0.z + a1.z; snn.w = a0.w + a1.w;
    *(float4*)&part_nn[s][cOff] = snn;

    float4 sen = en0;
    if (has_en1) { sen.x += en1.x; sen.y += en1.y; sen.z += en1.z; sen.w += en1.w; }
    *(float4*)&part_en[s][cOff] = sen;

    if (has_ev) *(float4*)&x0s[r][cOff] = ev;
    __syncthreads();

    // ---- reduce partials -> xbar ----
    if (t < BPB * D) {
        const int rr = t >> 6;       // batch row
        const int c  = t & 63;       // column
        float snn2 = 0.f, sen2 = 0.f;
        #pragma unroll
        for (int q = 0; q < 16 / BPB; ++q) {
            snn2 += part_nn[rr + BPB * q][c];
            sen2 += part_en[rr + BPB * q][c];
        }
        xbar[rr][c]     = sen2 * (1.0f / N0);   // mean e_n
        xbar[rr][D + c] = snn2 * (1.0f / NN);   // mean e_nn (mean of means == mean of all)
    }
    __syncthreads();

    // ---- phase 2a: agg0 = xbar @ W1  (128x128 matvec per row) ----
    const int j    = t & 127;   // output column
    const int half = t >> 7;    // k-range half
    {
        float acc[BPB];
        #pragma unroll
        for (int r2 = 0; r2 < BPB; ++r2) acc[r2] = 0.f;
        const int kbase = half * 64;
        #pragma unroll 4
        for (int k4 = 0; k4 < 16; ++k4) {
            const int k = kbase + k4 * 4;
            float4 xv[BPB];
            #pragma unroll
            for (int r2 = 0; r2 < BPB; ++r2)
                xv[r2] = *(const float4*)&xbar[r2][k];
            const float wa = W1[(k + 0) * H1 + j];
            const float wb = W1[(k + 1) * H1 + j];
            const float wc = W1[(k + 2) * H1 + j];
            const float wd = W1[(k + 3) * H1 + j];
            #pragma unroll
            for (int r2 = 0; r2 < BPB; ++r2)
                acc[r2] += xv[r2].x * wa + xv[r2].y * wb + xv[r2].z * wc + xv[r2].w * wd;
        }
        #pragma unroll
        for (int r2 = 0; r2 < BPB; ++r2) p2[half][r2][j] = acc[r2];
    }
    __syncthreads();
    for (int idx = t; idx < BPB * H1; idx += NT) {
        const int rr = idx >> 7, jj = idx & 127;
        x0s[rr][D + jj] = p2[0][rr][jj] + p2[1][rr][jj];
    }
    __syncthreads();

    // ---- phase 2b: h0 = sigmoid(x0 @ W0 + b0)  (192x128 matvec per row) ----
    {
        float acc[BPB];
        #pragma unroll
        for (int r2 = 0; r2 < BPB; ++r2) acc[r2] = 0.f;
        const int kbase = half * 96;
        #pragma unroll 4
        for (int k4 = 0; k4 < 24; ++k4) {
            const int k = kbase + k4 * 4;
            float4 xv[BPB];
            #pragma unroll
            for (int r2 = 0; r2 < BPB; ++r2)
                xv[r2] = *(const float4*)&x0s[r2][k];
            const float wa = W0[(k + 0) * H0 + j];
            const float wb = W0[(k + 1) * H0 + j];
            const float wc = W0[(k + 2) * H0 + j];
            const float wd = W0[(k + 3) * H0 + j];
            #pragma unroll
            for (int r2 = 0; r2 < BPB; ++r2)
                acc[r2] += xv[r2].x * wa + xv[r2].y * wb + xv[r2].z * wc + xv[r2].w * wd;
        }
        #pragma unroll
        for (int r2 = 0; r2 < BPB; ++r2) p2[half][r2][j] = acc[r2];
    }
    __syncthreads();
    for (int idx = t; idx < BPB * H0; idx += NT) {
        const int rr = idx >> 7, jj = idx & 127;
        const float v = p2[0][rr][jj] + p2[1][rr][jj] + b0[jj];
        out[(size_t)(bbase + rr) * H0 + jj] = 1.0f / (1.0f + __expf(-v));
    }
}

extern "C" void kernel_launch(void* const* d_in, const int* in_sizes, int n_in,
                              void* d_out, int out_size, void* d_ws, size_t ws_size,
                              hipStream_t stream) {
    const int*   inputs = (const int*)  d_in[0];
    const int*   neigh0 = (const int*)  d_in[1];
    const int*   neigh1 = (const int*)  d_in[2];
    const float* embed  = (const float*)d_in[3];
    const float* W1     = (const float*)d_in[4];
    const float* W0     = (const float*)d_in[5];
    const float* b0     = (const float*)d_in[6];
    float*       out    = (float*)d_out;

    const int B = in_sizes[0];           // 4096
    const int nblocks = B / BPB;         // 2048
    sage_fused<<<dim3(nblocks), dim3(NT), 0, stream>>>(
        inputs, neigh0, neigh1, embed, W1, W0, b0, out);
}